// Round 1
// 582.981 us; speedup vs baseline: 1.0508x; 1.0508x over previous
//
#include <hip/hip_runtime.h>
#include <cstdint>
#include <cstddef>

// Problem constants: B=8, N=256, H=128
// ws layout (floats):
//   Vx    @ 0        (2048*128)
//   Vnx   @ 262144
//   Ux    @ 524288
//   agg   @ 786432
//   esum  @ 1048576 (128), esumsq @ 1048704 (128)
//   nsum  @ 1048832 (128), nsumsq @ 1048960 (128)
//   (1049088..1049600 free — old k15 outputs, now folded into k2)
//   Wbf   @ 1049600  (Ue_w as bf16, 128x128 = 16384 shorts = 32 KB)

typedef float  f4v  __attribute__((ext_vector_type(4)));
typedef short  s8v  __attribute__((ext_vector_type(8)));

__device__ __forceinline__ unsigned short f2bf(float x) {
    unsigned u = __builtin_bit_cast(unsigned, x);
    u = (u + 0x7FFFu + ((u >> 16) & 1u)) >> 16;
    return (unsigned short)u;
}

__device__ __forceinline__ float sigmoid_f(float v) {
    float e = exp2f(-1.44269504088896f * v);     // v_exp_f32
    return __builtin_amdgcn_rcpf(1.0f + e);      // v_rcp_f32, ~1ulp: fine vs 0.165 thr
}

// ---------------- K0: Vx/Vnx/Ux projections + W->bf16 precompute ----------------
__global__ __launch_bounds__(256) void k0_proj(
    const float* __restrict__ x,
    const float* __restrict__ Ve_w, const float* __restrict__ Ve_b,
    const float* __restrict__ Vn_w, const float* __restrict__ Vn_b,
    const float* __restrict__ Un_w, const float* __restrict__ Un_b,
    const float* __restrict__ Ue_w,
    float* __restrict__ ws)
{
    int bid = blockIdx.x;
    int tid = threadIdx.x;

    if (bid >= 768) {                  // blocks 768..771: convert Ue_w -> bf16 once
        int g = (bid - 768) * 256 + tid;           // 0..1023, 16 elems each
        const float4* src = (const float4*)(Ue_w + g * 16);
        unsigned short* Wbf = (unsigned short*)(ws + 1049600);
        float4 v0 = src[0], v1 = src[1], v2 = src[2], v3 = src[3];
        s8v p0, p1;
        p0[0] = (short)f2bf(v0.x); p0[1] = (short)f2bf(v0.y);
        p0[2] = (short)f2bf(v0.z); p0[3] = (short)f2bf(v0.w);
        p0[4] = (short)f2bf(v1.x); p0[5] = (short)f2bf(v1.y);
        p0[6] = (short)f2bf(v1.z); p0[7] = (short)f2bf(v1.w);
        p1[0] = (short)f2bf(v2.x); p1[1] = (short)f2bf(v2.y);
        p1[2] = (short)f2bf(v2.z); p1[3] = (short)f2bf(v2.w);
        p1[4] = (short)f2bf(v3.x); p1[5] = (short)f2bf(v3.y);
        p1[6] = (short)f2bf(v3.z); p1[7] = (short)f2bf(v3.w);
        *(s8v*)(Wbf + g * 16)     = p0;
        *(s8v*)(Wbf + g * 16 + 8) = p1;
        return;
    }

    int m = bid >> 8;
    int rbase = (bid & 255) * 8;
    int h = tid & 127;
    int lr = tid >> 7;                 // 0..1

    const float* W; const float* bb; float* out;
    if (m == 0)      { W = Ve_w; bb = Ve_b; out = ws; }
    else if (m == 1) { W = Vn_w; bb = Vn_b; out = ws + 262144; }
    else             { W = Un_w; bb = Un_b; out = ws + 524288; }

    __shared__ __align__(16) float xs[8][128];
    for (int idx = tid; idx < 1024; idx += 256)
        xs[idx >> 7][idx & 127] = x[(rbase + (idx >> 7)) * 128 + (idx & 127)];

    if (bid == 0) {                    // zero esum/esumsq/nsum/nsumsq (512 floats)
        ws[1048576 + tid] = 0.0f;
        ws[1048576 + 256 + tid] = 0.0f;
    }
    __syncthreads();

    float acc[4] = {0.f, 0.f, 0.f, 0.f};
    float bv = bb[h];
    const float4* Wr = (const float4*)(W + h * 128);
    for (int k4 = 0; k4 < 32; ++k4) {
        float4 w4 = Wr[k4];
        int k = k4 * 4;
        #pragma unroll
        for (int q = 0; q < 4; ++q) {
            int rl = lr * 4 + q;
            acc[q] += w4.x * xs[rl][k] + w4.y * xs[rl][k + 1]
                    + w4.z * xs[rl][k + 2] + w4.w * xs[rl][k + 3];
        }
    }
    #pragma unroll
    for (int q = 0; q < 4; ++q)
        out[(rbase + lr * 4 + q) * 128 + h] = acc[q] + bv;
}

// ---------------- K1: pass A over e — stats + agg + node stats ----------------
// 32-row double-buffered tiles, W fragments in registers, 1 barrier/tile (no vmcnt drain)
__global__ __launch_bounds__(256, 4) void k1_stats(
    const float* __restrict__ e,
    const float* __restrict__ Ue_b,
    float* __restrict__ ws)
{
    const float* Vx  = ws;
    const float* Vnx = ws + 262144;
    const float* Ux  = ws + 524288;
    float* agg    = ws + 786432;
    float* esum   = ws + 1048576;
    float* esumsq = ws + 1048704;
    float* nsum   = ws + 1048832;
    float* nsumsq = ws + 1048960;
    const unsigned short* Wbf = (const unsigned short*)(ws + 1049600);

    int bid = blockIdx.x;              // b*256 + i
    int b = bid >> 8;
    int tid = threadIdx.x;
    int wave = tid >> 6;
    int lane = tid & 63;
    int col  = lane & 15;
    int quad = lane >> 4;
    int h0 = wave * 32 + col;
    int h1 = h0 + 16;

    __shared__ __align__(16) unsigned short Al[2][32 * 136];  // bf16 e-tiles, dbuf
    __shared__ float addi[128];                               // Ue_b + Vx[b,i,:]

    if (tid < 128) addi[tid] = Ue_b[tid] + Vx[bid * 128 + tid];

    // W fragments -> registers (L2-hit, once per block). B-frag for lane (col,quad)
    // at k-step kk is W[h][kk*32 + quad*8 .. +7]  (same mapping the LDS path used).
    s8v wf0[4], wf1[4];
    #pragma unroll
    for (int kk = 0; kk < 4; ++kk) {
        wf0[kk] = *(const s8v*)(Wbf + h0 * 128 + kk * 32 + quad * 8);
        wf1[kk] = *(const s8v*)(Wbf + h1 * 128 + kk * 32 + quad * 8);
    }

    const int arow = tid >> 4;          // 0..15
    const int akb  = (tid & 15) * 8;    // 0..120
    const float* eblk = e + (size_t)bid * 32768;

    // prefetch tile 0 (rows arow and arow+16)
    float4 pv0, pv1, pv2, pv3;
    {
        const float4* s0 = (const float4*)(eblk + arow * 128 + akb);
        const float4* s1 = (const float4*)(eblk + (arow + 16) * 128 + akb);
        pv0 = s0[0]; pv1 = s0[1]; pv2 = s1[0]; pv3 = s1[1];
    }

    float sum0 = 0.f, sum1 = 0.f, ss0 = 0.f, ss1 = 0.f, ag0 = 0.f, ag1 = 0.f;

    for (int jt = 0; jt < 8; ++jt) {
        unsigned short* Ac = &Al[jt & 1][0];
        {   // convert tile jt -> bf16 LDS (compiler inserts vmcnt wait for pv here)
            s8v pa, pb;
            pa[0] = (short)f2bf(pv0.x); pa[1] = (short)f2bf(pv0.y);
            pa[2] = (short)f2bf(pv0.z); pa[3] = (short)f2bf(pv0.w);
            pa[4] = (short)f2bf(pv1.x); pa[5] = (short)f2bf(pv1.y);
            pa[6] = (short)f2bf(pv1.z); pa[7] = (short)f2bf(pv1.w);
            pb[0] = (short)f2bf(pv2.x); pb[1] = (short)f2bf(pv2.y);
            pb[2] = (short)f2bf(pv2.z); pb[3] = (short)f2bf(pv2.w);
            pb[4] = (short)f2bf(pv3.x); pb[5] = (short)f2bf(pv3.y);
            pb[6] = (short)f2bf(pv3.z); pb[7] = (short)f2bf(pv3.w);
            *(s8v*)(&Ac[arow * 136 + akb])        = pa;
            *(s8v*)(&Ac[(arow + 16) * 136 + akb]) = pb;
        }
        if (jt < 7) {   // issue next-tile loads; they stay in flight across the barrier
            const float4* s0 = (const float4*)(eblk + ((jt + 1) * 32 + arow) * 128 + akb);
            const float4* s1 = (const float4*)(eblk + ((jt + 1) * 32 + arow + 16) * 128 + akb);
            pv0 = s0[0]; pv1 = s0[1]; pv2 = s1[0]; pv3 = s1[1];
        }
        // drain LDS only (writes visible + prior reads done); do NOT drain vmcnt
        asm volatile("s_waitcnt lgkmcnt(0)" ::: "memory");
        __builtin_amdgcn_s_barrier();

        #pragma unroll
        for (int js = 0; js < 2; ++js) {
            f4v acc0 = {0.f, 0.f, 0.f, 0.f}, acc1 = {0.f, 0.f, 0.f, 0.f};
            #pragma unroll
            for (int kk = 0; kk < 4; ++kk) {
                s8v a = *(const s8v*)(&Ac[(js * 16 + col) * 136 + kk * 32 + quad * 8]);
                acc0 = __builtin_amdgcn_mfma_f32_16x16x32_bf16(a, wf0[kk], acc0, 0, 0, 0);
                acc1 = __builtin_amdgcn_mfma_f32_16x16x32_bf16(a, wf1[kk], acc1, 0, 0, 0);
            }
            float ai0 = addi[h0], ai1 = addi[h1];
            #pragma unroll
            for (int r = 0; r < 4; ++r) {
                int j = jt * 32 + js * 16 + quad * 4 + r;
                const float* vxr = Vx  + (size_t)((b << 8) + j) * 128;
                const float* vnr = Vnx + (size_t)((b << 8) + j) * 128;
                float v0 = acc0[r] + ai0 + vxr[h0];
                float v1 = acc1[r] + ai1 + vxr[h1];
                sum0 += v0; ss0 += v0 * v0;
                sum1 += v1; ss1 += v1 * v1;
                ag0 += sigmoid_f(v0) * vnr[h0];
                ag1 += sigmoid_f(v1) * vnr[h1];
            }
        }
    }

    // quads partition j: reduce across quad bits (lanes 16,32)
    sum0 += __shfl_xor(sum0, 16); sum0 += __shfl_xor(sum0, 32);
    sum1 += __shfl_xor(sum1, 16); sum1 += __shfl_xor(sum1, 32);
    ss0  += __shfl_xor(ss0, 16);  ss0  += __shfl_xor(ss0, 32);
    ss1  += __shfl_xor(ss1, 16);  ss1  += __shfl_xor(ss1, 32);
    ag0  += __shfl_xor(ag0, 16);  ag0  += __shfl_xor(ag0, 32);
    ag1  += __shfl_xor(ag1, 16);  ag1  += __shfl_xor(ag1, 32);

    if (lane < 16) {   // col==lane; each wave owns disjoint h
        atomicAdd(&esum[h0], sum0);
        atomicAdd(&esumsq[h0], ss0);
        atomicAdd(&esum[h1], sum1);
        atomicAdd(&esumsq[h1], ss1);
        agg[bid * 128 + h0] = ag0;
        agg[bid * 128 + h1] = ag1;
        // node-side: x_new row bid is final here -> accumulate BN stats
        float v0 = Ux[bid * 128 + h0] + ag0;
        float v1 = Ux[bid * 128 + h1] + ag1;
        atomicAdd(&nsum[h0], v0);
        atomicAdd(&nsumsq[h0], v0 * v0);
        atomicAdd(&nsum[h1], v1);
        atomicAdd(&nsumsq[h1], v1 * v1);
    }
}

// ---------------- K2: pass B over e — recompute e_new, BN+ReLU+residual; + x_out ----------------
// Same dbuf structure as K1; BN finalize folded in; direct register stores; residual
// via L1-hit re-read of e (tile was just staged from the same lines).
__global__ __launch_bounds__(256, 4) void k2_apply(
    const float* __restrict__ e,
    const float* __restrict__ x,
    const float* __restrict__ Ue_b,
    const float* __restrict__ bne_w, const float* __restrict__ bne_b,
    const float* __restrict__ bnn_w, const float* __restrict__ bnn_b,
    const float* __restrict__ ws, float* __restrict__ out_x,
    float* __restrict__ out_e)
{
    const float* Vx   = ws;
    const float* Ux   = ws + 524288;
    const float* agg  = ws + 786432;
    const float* esum = ws + 1048576;
    const float* esumsq = ws + 1048704;
    const float* nsum = ws + 1048832;
    const float* nsumsq = ws + 1048960;
    const unsigned short* Wbf = (const unsigned short*)(ws + 1049600);

    int bid = blockIdx.x;
    int b = bid >> 8;
    int tid = threadIdx.x;
    int wave = tid >> 6;
    int lane = tid & 63;
    int col  = lane & 15;
    int quad = lane >> 4;
    int h0 = wave * 32 + col;
    int h1 = h0 + 16;

    __shared__ __align__(16) unsigned short Al[2][32 * 136];
    __shared__ float addi[128], escl[128], eshl[128];

    if (tid < 128) {
        // BN finalize (was k15): per-block recompute, ~20 VALU + 2 rsqrt
        float m  = esum[tid]   * (1.0f / 524288.0f);
        float q  = esumsq[tid] * (1.0f / 524288.0f);
        float rs = rsqrtf(q - m * m + 1e-5f);
        float sc = rs * bne_w[tid];
        escl[tid] = sc;
        eshl[tid] = bne_b[tid] - m * sc;
        addi[tid] = Ue_b[tid] + Vx[bid * 128 + tid];

        float mn  = nsum[tid]   * (1.0f / 2048.0f);
        float qn  = nsumsq[tid] * (1.0f / 2048.0f);
        float rsn = rsqrtf(qn - mn * mn + 1e-5f);
        float scn = rsn * bnn_w[tid];
        float shn = bnn_b[tid] - mn * scn;
        float v = Ux[bid * 128 + tid] + agg[bid * 128 + tid];
        out_x[bid * 128 + tid] = x[bid * 128 + tid] + fmaxf(v * scn + shn, 0.0f);
    }

    s8v wf0[4], wf1[4];
    #pragma unroll
    for (int kk = 0; kk < 4; ++kk) {
        wf0[kk] = *(const s8v*)(Wbf + h0 * 128 + kk * 32 + quad * 8);
        wf1[kk] = *(const s8v*)(Wbf + h1 * 128 + kk * 32 + quad * 8);
    }

    const int arow = tid >> 4;
    const int akb  = (tid & 15) * 8;
    const float* eblk = e + (size_t)bid * 32768;
    float* oblk = out_e + (size_t)bid * 32768;

    float4 pv0, pv1, pv2, pv3;
    {
        const float4* s0 = (const float4*)(eblk + arow * 128 + akb);
        const float4* s1 = (const float4*)(eblk + (arow + 16) * 128 + akb);
        pv0 = s0[0]; pv1 = s0[1]; pv2 = s1[0]; pv3 = s1[1];
    }

    for (int jt = 0; jt < 8; ++jt) {
        unsigned short* Ac = &Al[jt & 1][0];
        {
            s8v pa, pb;
            pa[0] = (short)f2bf(pv0.x); pa[1] = (short)f2bf(pv0.y);
            pa[2] = (short)f2bf(pv0.z); pa[3] = (short)f2bf(pv0.w);
            pa[4] = (short)f2bf(pv1.x); pa[5] = (short)f2bf(pv1.y);
            pa[6] = (short)f2bf(pv1.z); pa[7] = (short)f2bf(pv1.w);
            pb[0] = (short)f2bf(pv2.x); pb[1] = (short)f2bf(pv2.y);
            pb[2] = (short)f2bf(pv2.z); pb[3] = (short)f2bf(pv2.w);
            pb[4] = (short)f2bf(pv3.x); pb[5] = (short)f2bf(pv3.y);
            pb[6] = (short)f2bf(pv3.z); pb[7] = (short)f2bf(pv3.w);
            *(s8v*)(&Ac[arow * 136 + akb])        = pa;
            *(s8v*)(&Ac[(arow + 16) * 136 + akb]) = pb;
        }
        if (jt < 7) {
            const float4* s0 = (const float4*)(eblk + ((jt + 1) * 32 + arow) * 128 + akb);
            const float4* s1 = (const float4*)(eblk + ((jt + 1) * 32 + arow + 16) * 128 + akb);
            pv0 = s0[0]; pv1 = s0[1]; pv2 = s1[0]; pv3 = s1[1];
        }
        asm volatile("s_waitcnt lgkmcnt(0)" ::: "memory");
        __builtin_amdgcn_s_barrier();

        #pragma unroll
        for (int js = 0; js < 2; ++js) {
            f4v acc0 = {0.f, 0.f, 0.f, 0.f}, acc1 = {0.f, 0.f, 0.f, 0.f};
            #pragma unroll
            for (int kk = 0; kk < 4; ++kk) {
                s8v a = *(const s8v*)(&Ac[(js * 16 + col) * 136 + kk * 32 + quad * 8]);
                acc0 = __builtin_amdgcn_mfma_f32_16x16x32_bf16(a, wf0[kk], acc0, 0, 0, 0);
                acc1 = __builtin_amdgcn_mfma_f32_16x16x32_bf16(a, wf1[kk], acc1, 0, 0, 0);
            }
            float ai0 = addi[h0], ai1 = addi[h1];
            float sc0 = escl[h0], sh0 = eshl[h0];
            float sc1 = escl[h1], sh1 = eshl[h1];
            #pragma unroll
            for (int r = 0; r < 4; ++r) {
                int j = jt * 32 + js * 16 + quad * 4 + r;
                const float* vxr = Vx + (size_t)((b << 8) + j) * 128;
                float v0 = acc0[r] + ai0 + vxr[h0];
                float v1 = acc1[r] + ai1 + vxr[h1];
                float r0 = fmaxf(v0 * sc0 + sh0, 0.0f);
                float r1 = fmaxf(v1 * sc1 + sh1, 0.0f);
                // residual: L1/L2-hit re-read of e (tile staged moments ago)
                oblk[j * 128 + h0] = eblk[j * 128 + h0] + r0;
                oblk[j * 128 + h1] = eblk[j * 128 + h1] + r1;
            }
        }
    }
}

extern "C" void kernel_launch(void* const* d_in, const int* in_sizes, int n_in,
                              void* d_out, int out_size, void* d_ws, size_t ws_size,
                              hipStream_t stream)
{
    const float* x     = (const float*)d_in[0];
    const float* e     = (const float*)d_in[1];
    const float* Ue_w  = (const float*)d_in[2];
    const float* Ue_b  = (const float*)d_in[3];
    const float* Ve_w  = (const float*)d_in[4];
    const float* Ve_b  = (const float*)d_in[5];
    const float* Un_w  = (const float*)d_in[6];
    const float* Un_b  = (const float*)d_in[7];
    const float* Vn_w  = (const float*)d_in[8];
    const float* Vn_b  = (const float*)d_in[9];
    const float* bne_w = (const float*)d_in[10];
    const float* bne_b = (const float*)d_in[11];
    const float* bnn_w = (const float*)d_in[12];
    const float* bnn_b = (const float*)d_in[13];
    float* ws    = (float*)d_ws;
    float* out_x = (float*)d_out;
    float* out_e = (float*)d_out + 262144;

    hipLaunchKernelGGL(k0_proj, dim3(772), dim3(256), 0, stream,
                       x, Ve_w, Ve_b, Vn_w, Vn_b, Un_w, Un_b, Ue_w, ws);
    hipLaunchKernelGGL(k1_stats, dim3(2048), dim3(256), 0, stream,
                       e, Ue_b, ws);
    hipLaunchKernelGGL(k2_apply, dim3(2048), dim3(256), 0, stream,
                       e, x, Ue_b, bne_w, bne_b, bnn_w, bnn_b, ws, out_x, out_e);
}